// Round 4
// baseline (124.597 us; speedup 1.0000x reference)
//
#include <hip/hip_runtime.h>
#include <hip/hip_bf16.h>

typedef __attribute__((ext_vector_type(8))) short short8;
typedef __attribute__((ext_vector_type(16))) float f32x16;
typedef __fp16 h2 __attribute__((ext_vector_type(2)));
typedef unsigned short ushort_t;

#define DEVFN static __device__ __forceinline__

DEVFN float bf2f(unsigned short u){
  union { unsigned int i; float f; } v; v.i = ((unsigned int)u) << 16; return v.f;
}
DEVFN unsigned short f2bf(float f){
  unsigned int u = __float_as_uint(f);
  unsigned int r = u + 0x7FFFu + ((u >> 16) & 1u);
  return (unsigned short)(r >> 16);
}
DEVFN unsigned int pkbf(float lo, float hi){
  __hip_bfloat162 h = __float22bfloat162_rn(make_float2(lo, hi));
  return *reinterpret_cast<unsigned int*>(&h);
}
DEVFN h2 pkrtz(float a, float b){ return __builtin_amdgcn_cvt_pkrtz(a, b); }
#if __has_builtin(__builtin_amdgcn_fdot2)
DEVFN float fdot2(h2 a, h2 b, float c){ return __builtin_amdgcn_fdot2(a, b, c, false); }
#else
DEVFN float fdot2(h2 a, h2 b, float c){ return c + (float)a[0]*(float)b[0] + (float)a[1]*(float)b[1]; }
#endif
DEVFN float tanh_fast(float x){
  float t = __builtin_amdgcn_exp2f(x * 2.885390081777926815f);
  return 1.0f - 2.0f * __builtin_amdgcn_rcpf(t + 1.0f);
}
DEVFN void gl_lds16(const ushort_t* g, ushort_t* l){
  __builtin_amdgcn_global_load_lds(
      (const __attribute__((address_space(1))) void*)g,
      (__attribute__((address_space(3))) void*)l, 16, 0, 0);
}
DEVFN void vm8(){ asm volatile("s_waitcnt vmcnt(8)" ::: "memory"); }
DEVFN void vm6(){ asm volatile("s_waitcnt vmcnt(6)" ::: "memory"); }
DEVFN void vm2(){ asm volatile("s_waitcnt vmcnt(2)" ::: "memory"); }
DEVFN void vm0(){ asm volatile("s_waitcnt vmcnt(0)" ::: "memory"); }
// shared A/B K-slot mapping for 32x32x16 MFMA fragments
DEVFN int kmap(int h, int j){ return 4*h + (j & 3) + 8*(j >> 2); }

// ---------------- weight bake ----------------
// wfrag: per-WG step-tiles. tile(gh,nh,f) = 12KB contiguous:
//   hw index = ((gh*2+nh)*64 + f)*6144 + b*512 + lane*8 + j
//   b = (q*3 + l)*2 + nt ; k = nt*32 + (lane&31); path = nh;
//   g(j) = gh*32 + q*16 + kmap(lane>>5, j)
__global__ void bake_w0(const float* __restrict__ wx0, const float* __restrict__ wy0,
                        ushort_t* __restrict__ wfrag){
  int slot = blockIdx.x * 256 + threadIdx.x;      // < 196608
  int lane = slot & 63;
  int r = slot >> 6;
  int b = r % 12; r /= 12;
  int f = r % 64; r /= 64;
  int nh = r & 1; int gh = r >> 1;
  int nt = b & 1; int lq = b >> 1;
  int q = lq / 3; int l = lq % 3;
  int h = lane >> 5;
  int k = nt*32 + (lane & 31);
  const float* w = nh ? wy0 : wx0;
  unsigned int pk[4];
#pragma unroll
  for (int jj = 0; jj < 4; ++jj){
    int g0 = gh*32 + q*16 + kmap(h, 2*jj);
    int g1 = gh*32 + q*16 + kmap(h, 2*jj + 1);
    unsigned int b0 = f2bf(w[((k*64 + f)*64 + g0)*3 + l]);
    unsigned int b1 = f2bf(w[((k*64 + f)*64 + g1)*3 + l]);
    pk[jj] = b0 | (b1 << 16);
  }
  *reinterpret_cast<uint4*>(wfrag + (size_t)slot * 8) = make_uint4(pk[0], pk[1], pk[2], pk[3]);
}

__global__ void bake_wh(const float* __restrict__ wxh, const float* __restrict__ wyh,
                        ushort_t* __restrict__ whfrag){
  int slot = blockIdx.x * 256 + threadIdx.x;      // < 2048
  int lane = slot & 63;
  int q = slot >> 6;
  int nt = q & 1; q >>= 1;
  int c  = q & 3; q >>= 2;
  int path = q & 1; int layer = q >> 1;
  const float* w = path ? wyh : wxh;
  int n = nt*32 + (lane & 31);
  int h = lane >> 5;
  unsigned int pk[4];
#pragma unroll
  for (int jj = 0; jj < 4; ++jj){
    int k0 = c*16 + kmap(h, 2*jj);
    int k1 = c*16 + kmap(h, 2*jj + 1);
    unsigned int b0 = f2bf(w[layer*4096 + k0*64 + n]);
    unsigned int b1 = f2bf(w[layer*4096 + k1*64 + n]);
    pk[jj] = b0 | (b1 << 16);
  }
  *reinterpret_cast<uint4*>(whfrag + (size_t)slot * 8) = make_uint4(pk[0], pk[1], pk[2], pk[3]);
}

__global__ void bake_wf(const float* __restrict__ wxf, const float* __restrict__ wyf,
                        ushort_t* __restrict__ wffrag){
  int slot = blockIdx.x * 256 + threadIdx.x;      // < 3072
  int lane = slot & 63;
  int q = slot >> 6;            // < 48
  int ntf = q % 6;
  int q2 = q / 6;
  int c = q2 & 3; int path = q2 >> 2;
  const float* w = path ? wyf : wxf;
  int n = ntf*32 + (lane & 31);
  int lw = n >> 6, fw = n & 63;
  int h = lane >> 5;
  unsigned int pk[4];
#pragma unroll
  for (int jj = 0; jj < 4; ++jj){
    int k0 = c*16 + kmap(h, 2*jj);
    int k1 = c*16 + kmap(h, 2*jj + 1);
    unsigned int b0 = f2bf(w[(lw*64 + fw)*64 + k0]);
    unsigned int b1 = f2bf(w[(lw*64 + fw)*64 + k1]);
    pk[jj] = b0 | (b1 << 16);
  }
  *reinterpret_cast<uint4*>(wffrag + (size_t)slot * 8) = make_uint4(pk[0], pk[1], pk[2], pk[3]);
}

// ---------------- main fused GEMM ----------------
// Grid 256 = Mblk(64, 128 pts) x gh(2) x nh(2); 512 thr = 8 waves = mt(4) x q(2).
// A-fragments generated in registers (fdot2 f16); B via LDS ring[4][12KB];
// y via LDS f32 [4][128][12]; one raw s_barrier/step, counted vmcnt.
// LDS: B ring 49152 B @0 ; y 24576 B @49152 ; total 73728.
__global__ __launch_bounds__(512, 1)
void gemm3(const float* __restrict__ x, const float* __restrict__ y,
           const ushort_t* __restrict__ wfrag, float* __restrict__ mixp){
  extern __shared__ char lds[];
  ushort_t* ringhw = (ushort_t*)lds;
  float* ybase = (float*)(lds + 49152);

  const int t = threadIdx.x;
  const int bid = blockIdx.x;
  // XCD-grouping swizzle: 4 sibling (gh,nh) WGs of one Mblk -> same XCD
  const int ml = bid & 7, cmb = (bid >> 3) & 3, mh = bid >> 5;
  const int Mblk = mh*8 + ml;
  const int gh = cmb >> 1, nh = cmb & 1;
  const int pbase = Mblk * 128;

  const int lane = t & 63, w = t >> 6;
  const int mt = w & 3, q = w >> 2;
  const int h = lane >> 5, prow = lane & 31;
  const int p = pbase + mt*32 + prow;
  const int gq = gh*32 + q*16;
  const int rowloc = mt*32 + prow;

  // y staging role: all 512 threads; 4 threads/row
  const int yrow = t >> 2, si = t & 3;
  const int s8 = (si == 0) ? 8 : si;
  const float* yglob = y + (size_t)(pbase + yrow) * 576;

  // B staging role: waves 0..5
  const ushort_t* wgtile = wfrag + (size_t)((gh*2 + nh) * 64) * 6144;
  const int bso = (w*128 + lane) * 8;

  // ---- xg init: 8 g's (own k-slots), f16 pairs grouped by l ----
  h2 xg[8][6];
#pragma unroll
  for (int j = 0; j < 8; ++j){
    int g = gq + 4*h + (j & 3) + 8*(j >> 2);
    const float* xp = x + (size_t)p*576 + g*9;
    const float* yp = y + (size_t)p*576 + g*9;
    float x1 = xp[1], x2 = xp[2], x3 = xp[3];
    float y0 = yp[0], y1 = yp[1], y2 = yp[2], y3 = yp[3];
    float gate = (x2*y3 - x3*y2)*y0 + (x3*y1 - x1*y3)*y1 + (x1*y2 - x2*y1)*y2;
    float v0 = xp[0]*gate, v1 = x1*gate, v2 = x2*gate, v3 = x3*gate;
    float v4 = xp[4]*gate, v5 = xp[5]*gate, v6 = xp[6]*gate, v7 = xp[7]*gate, v8 = xp[8]*gate;
    xg[j][0] = pkrtz(v0, 0.f);
    xg[j][1] = pkrtz(v1, v2);
    xg[j][2] = pkrtz(v3, 0.f);
    xg[j][3] = pkrtz(v4, v5);
    xg[j][4] = pkrtz(v6, v7);
    xg[j][5] = pkrtz(v8, 0.f);
  }

  f32x16 acc0, acc1;
#pragma unroll
  for (int r = 0; r < 16; ++r){ acc0[r] = 0.f; acc1[r] = 0.f; }

  float ys0[6], ys1[6];

  auto yissue = [&](int f4, float* dst){
    if (f4 < 64){
      const float* g0 = yglob + f4*9;
      dst[0] = g0[si]; dst[1] = g0[si + 4]; dst[2] = g0[s8];
      const float* g1 = g0 + 9;
      dst[3] = g1[si]; dst[4] = g1[si + 4]; dst[5] = g1[s8];
    }
  };
  auto ywrite = [&](int f2, const float* src){
    if (f2 < 64){
      float* b0 = ybase + ((size_t)(f2 & 3)*128 + yrow)*12;
      b0[si] = src[0]; b0[si + 4] = src[1]; b0[s8] = src[2];
      float* b1 = ybase + ((size_t)((f2 + 1) & 3)*128 + yrow)*12;
      b1[si] = src[3]; b1[si + 4] = src[4]; b1[s8] = src[5];
    }
  };
  auto bissue = [&](int fb){
    if (w < 6 && fb < 64){
      const ushort_t* src = wgtile + (size_t)fb * 6144 + bso;
      ushort_t* dst = ringhw + (size_t)(fb & 3) * 6144 + bso;
      gl_lds16(src, dst);
      gl_lds16(src + 512, dst + 512);
    }
  };
  auto agen_mfma = [&](int f){
    const float* yr = ybase + ((size_t)(f & 3)*128 + rowloc)*12;
    float4 r0 = *(const float4*)yr;
    float4 r1 = *(const float4*)(yr + 4);
    float  r8 = yr[8];
    h2 p0 = pkrtz(r0.x, 0.f), p1 = pkrtz(r0.y, r0.z), p2 = pkrtz(r0.w, 0.f);
    h2 p3 = pkrtz(r1.x, r1.y), p4 = pkrtz(r1.z, r1.w), p5 = pkrtz(r8, 0.f);
    float a0[8], a1[8], a2[8];
#pragma unroll
    for (int j = 0; j < 8; ++j){
      a0[j] = fdot2(xg[j][0], p0, 0.f);
      a1[j] = fdot2(xg[j][2], p2, fdot2(xg[j][1], p1, 0.f));
      a2[j] = fdot2(xg[j][5], p5, fdot2(xg[j][4], p4, fdot2(xg[j][3], p3, 0.f)));
    }
    union { uint4 u; short8 s; } fr[3];
    fr[0].u = make_uint4(pkbf(a0[0],a0[1]), pkbf(a0[2],a0[3]), pkbf(a0[4],a0[5]), pkbf(a0[6],a0[7]));
    fr[1].u = make_uint4(pkbf(a1[0],a1[1]), pkbf(a1[2],a1[3]), pkbf(a1[4],a1[5]), pkbf(a1[6],a1[7]));
    fr[2].u = make_uint4(pkbf(a2[0],a2[1]), pkbf(a2[2],a2[3]), pkbf(a2[4],a2[5]), pkbf(a2[6],a2[7]));
    const ushort_t* br = ringhw + (size_t)(f & 3)*6144 + q*3072 + (size_t)lane*8;
#pragma unroll
    for (int l = 0; l < 3; ++l){
      short8 b0 = *(const short8*)(br + (l*2    )*512);
      short8 b1 = *(const short8*)(br + (l*2 + 1)*512);
      acc0 = __builtin_amdgcn_mfma_f32_32x32x16_bf16(fr[l].s, b0, acc0, 0, 0, 0);
      acc1 = __builtin_amdgcn_mfma_f32_32x32x16_bf16(fr[l].s, b1, acc1, 0, 0, 0);
    }
  };
  auto endstep = [&](){
    asm volatile("s_waitcnt lgkmcnt(0)" ::: "memory");
    __builtin_amdgcn_s_barrier();
  };

  // ---- prologue ----
  bissue(0);            // slot 0
  bissue(1);            // slot 1
  yissue(0, ys0);       // y(0),y(1)
  yissue(2, ys1);       // y(2),y(3)
  vm0();
  ywrite(0, ys0);       // bufs 0,1
  endstep();

  // ---- main loop: 4-step bodies (2 pairs) for static ys rotation ----
#pragma unroll 1
  for (int f = 0; f < 64; f += 4){
    // even step f: write y(f+2,f+3) from ys1, issue y(f+4,f+5)->ys0
    bissue(f + 2);
    yissue(f + 4, ys0);
    if (w < 6){ if (f <= 58) vm8(); else if (f == 60) vm2(); else vm0(); }
    else      { if (f <= 58) vm6(); else if (f == 60) vm0(); }
    ywrite(f + 2, ys1);
    agen_mfma(f);
    endstep();
    // odd step f+1
    bissue(f + 3);
    if (w < 6){ if (f + 1 <= 59) vm8(); else if (f + 1 == 61) vm2(); }
    agen_mfma(f + 1);
    endstep();
    // even step f+2: write from ys0, issue -> ys1
    bissue(f + 4);
    yissue(f + 6, ys1);
    if (w < 6){ if (f + 2 <= 58) vm8(); else if (f + 2 == 60) vm2(); else vm0(); }
    else      { if (f + 2 <= 58) vm6(); else if (f + 2 == 60) vm0(); }
    ywrite(f + 4, ys0);
    agen_mfma(f + 2);
    endstep();
    // odd step f+3
    bissue(f + 5);
    if (w < 6){ if (f + 3 <= 59) vm8(); else if (f + 3 == 61) vm2(); }
    agen_mfma(f + 3);
    endstep();
  }

  // ---- write partial mix (K-partial index gh*2+q) ----
  {
    const int col = lane & 31;
    const size_t pb = (size_t)pbase + mt*32;
    float* mp = mixp + (size_t)(gh*2 + q) * 1048576;
#pragma unroll
    for (int r = 0; r < 16; ++r){
      int rowm = (r & 3) + 8*(r >> 2) + 4*h;
      float* d = mp + (pb + rowm)*128 + nh*64 + col;
      d[0]  = acc0[r];
      d[32] = acc1[r];
    }
  }
}

// ---------------- MLP + final einsum + epilogue ----------------
__global__ __launch_bounds__(256, 1)
void mlp_final(const float* __restrict__ x, const float* __restrict__ y,
               const ushort_t* __restrict__ whfrag,
               const ushort_t* __restrict__ wffrag,
               const float* __restrict__ mixp, float* __restrict__ out){
  extern __shared__ char ldsm[];
  ushort_t* hw = (ushort_t*)ldsm;
  const int t = threadIdx.x;
  const long pbase = (long)blockIdx.x * 32;

  {  // load mix = sum of 4 partials -> act buf0 (bf16)
    int p = t >> 3, n0 = (t & 7) * 16;
    const float* src = mixp + (pbase + p)*128 + n0;
    int path = n0 >> 6, nn = n0 & 63;
    ushort_t* dst = hw + (path*2)*2176 + p*68 + nn;
#pragma unroll
    for (int q2 = 0; q2 < 16; ++q2){
      float v = src[q2] + src[q2 + 1048576] + src[q2 + 2097152] + src[q2 + 3145728];
      dst[q2] = f2bf(v);
    }
  }
  __syncthreads();

  const int w = t >> 6, lane = t & 63;
  const int path = w >> 1, ntw = w & 1;
  const int prow = lane & 31, h = lane >> 5;
  int cur = 0;

#pragma unroll
  for (int layer = 0; layer < 2; ++layer){
    const ushort_t* act = hw + (path*2 + cur)*2176;
    f32x16 acc;
#pragma unroll
    for (int r = 0; r < 16; ++r) acc[r] = 0.f;
#pragma unroll
    for (int c = 0; c < 4; ++c){
      int ab = prow*68 + c*16 + 4*h;
      ushort4 lo = *(const ushort4*)&act[ab];
      ushort4 hi = *(const ushort4*)&act[ab + 8];
      short8 av; av[0]=lo.x; av[1]=lo.y; av[2]=lo.z; av[3]=lo.w;
      av[4]=hi.x; av[5]=hi.y; av[6]=hi.z; av[7]=hi.w;
      short8 bv = *(const short8*)(whfrag + ((((layer*2 + path)*4 + c)*2 + ntw)*512 + lane*8));
      acc = __builtin_amdgcn_mfma_f32_32x32x16_bf16(av, bv, acc, 0, 0, 0);
    }
    ushort_t* nact = hw + (path*2 + (cur ^ 1))*2176;
#pragma unroll
    for (int r = 0; r < 16; ++r){
      int p = (r & 3) + 8*(r >> 2) + 4*h;
      nact[p*68 + ntw*32 + prow] = f2bf(tanh_fast(acc[r]));
    }
    cur ^= 1;
    __syncthreads();
  }

  {  // final einsum: o[p][n=l*64+f], N=192 -> each wave 3 n-tiles
    const ushort_t* act = hw + (path*2 + cur)*2176;
    ushort_t* ob = hw + 8704 + path*6272;
#pragma unroll
    for (int e = 0; e < 3; ++e){
      int ntf = ntw*3 + e;
      f32x16 acc;
#pragma unroll
      for (int r = 0; r < 16; ++r) acc[r] = 0.f;
#pragma unroll
      for (int c = 0; c < 4; ++c){
        int ab = prow*68 + c*16 + 4*h;
        ushort4 lo = *(const ushort4*)&act[ab];
        ushort4 hi = *(const ushort4*)&act[ab + 8];
        short8 av; av[0]=lo.x; av[1]=lo.y; av[2]=lo.z; av[3]=lo.w;
        av[4]=hi.x; av[5]=hi.y; av[6]=hi.z; av[7]=hi.w;
        short8 bv = *(const short8*)(wffrag + (((path*4 + c)*6 + ntf)*512 + lane*8));
        acc = __builtin_amdgcn_mfma_f32_32x32x16_bf16(av, bv, acc, 0, 0, 0);
      }
#pragma unroll
      for (int r = 0; r < 16; ++r){
        int p = (r & 3) + 8*(r >> 2) + 4*h;
        ob[p*196 + ntf*32 + prow] = f2bf(tanh_fast(acc[r]));
      }
    }
  }
  __syncthreads();

  const ushort_t* oxb = hw + 8704;
  const ushort_t* oyb = hw + 8704 + 6272;
#pragma unroll 1
  for (int rep = 0; rep < 8; ++rep){
    int idx = t + rep*256;
    int p = idx >> 6, fq = idx & 63;
    const float* xr = x + ((pbase + p)*64 + fq)*9;
    const float* yr = y + ((pbase + p)*64 + fq)*9;
    float xv[9], yv[9];
#pragma unroll
    for (int s = 0; s < 9; ++s){ xv[s] = xr[s]; yv[s] = yr[s]; }
    float c0 = xv[2]*yv[3] - xv[3]*yv[2];
    float c1 = xv[3]*yv[1] - xv[1]*yv[3];
    float c2 = xv[1]*yv[2] - xv[2]*yv[1];
    float gate = c0*yv[0] + c1*yv[1] + c2*yv[2];
    float ox0 = bf2f(oxb[p*196 + fq]);
    float ox1 = bf2f(oxb[p*196 + 64 + fq]);
    float ox2 = bf2f(oxb[p*196 + 128 + fq]);
    float oy0 = bf2f(oyb[p*196 + fq]);
    float oy1 = bf2f(oyb[p*196 + 64 + fq]);
    float oy2 = bf2f(oyb[p*196 + 128 + fq]);
    float* orow = out + ((pbase + p)*64 + fq)*9;
    orow[0] = ox0*xv[0]*gate + oy0*yv[0];
#pragma unroll
    for (int s = 1; s < 4; ++s) orow[s] = ox1*xv[s]*gate + oy1*yv[s];
#pragma unroll
    for (int s = 4; s < 9; ++s) orow[s] = ox2*xv[s]*gate + oy2*yv[s];
  }
}

extern "C" void kernel_launch(void* const* d_in, const int* in_sizes, int n_in,
                              void* d_out, int out_size, void* d_ws, size_t ws_size,
                              hipStream_t stream){
  (void)in_sizes; (void)n_in; (void)out_size; (void)ws_size;
  const float* x   = (const float*)d_in[0];
  const float* y   = (const float*)d_in[1];
  const float* wx0 = (const float*)d_in[2];
  const float* wy0 = (const float*)d_in[3];
  const float* wxh = (const float*)d_in[4];
  const float* wyh = (const float*)d_in[5];
  const float* wxf = (const float*)d_in[6];
  const float* wyf = (const float*)d_in[7];
  float* out = (float*)d_out;
  char* ws = (char*)d_ws;
  ushort_t* wfrag  = (ushort_t*)(ws);             // 3,145,728 B
  ushort_t* whfrag = (ushort_t*)(ws + 3145728);   //    32,768 B
  ushort_t* wffrag = (ushort_t*)(ws + 3178496);   //    49,152 B
  float* mixp = (float*)(ws + 3227648);           // 4 x 4,194,304 B

  (void)hipFuncSetAttribute((const void*)gemm3,
        hipFuncAttributeMaxDynamicSharedMemorySize, 73728);
  (void)hipFuncSetAttribute((const void*)mlp_final,
        hipFuncAttributeMaxDynamicSharedMemorySize, 43520);

  hipLaunchKernelGGL(bake_w0, dim3(768), dim3(256), 0, stream, wx0, wy0, wfrag);
  hipLaunchKernelGGL(bake_wh, dim3(8),   dim3(256), 0, stream, wxh, wyh, whfrag);
  hipLaunchKernelGGL(bake_wf, dim3(12),  dim3(256), 0, stream, wxf, wyf, wffrag);
  hipLaunchKernelGGL(gemm3, dim3(256), dim3(512), 73728, stream, x, y, wfrag, mixp);
  hipLaunchKernelGGL(mlp_final, dim3(256), dim3(256), 42496, stream, x, y, whfrag, wffrag, mixp, out);
}